// Round 5
// baseline (243.988 us; speedup 1.0000x reference)
//
#include <hip/hip_runtime.h>
#include <math.h>

// LeakyAvg: y[t] = k[t] + alpha_h * y[t-1], alpha = exp(-|beta|*10) in [e^-5, e^-0.5].
// alpha^16 <= e^-8 -> 16-step halo warm-up makes 8-row chunks independent.
//
// R5 post-mortem of R0-R4: 2.5-2.8 TB/s REGARDLESS of per-wave MLP depth or
// access contiguity (R4 was fully linear DMA + contiguous stores: same 82us).
// Common factor: every version fully drains vmcnt at each phase boundary, and
// only ~4 block-slots/CU exist -> per CU the memory queue empties every phase.
// 82.7us/16 blocks = 5.2us per 69.7KB slot = 13.5 GB/s/CU exposed-latency rate.
//
// R5 = T3/T4 pipeline: persistent block, 8 tiles of 64 rows, double-buffered
// LDS DMA with COUNTED vmcnt (16 = prev stores + next tile's DMA stay in
// flight; never 0 in the loop). Each block always has a full 16KB tile
// outstanding; 4 blocks/CU -> 64KB/CU in flight continuously.
// Halo now comes from the previous tile in LDS (4KB H slot, copied per tile):
// HBM halo re-read drops 12.5% -> 1.6% (span starts only).
//
// Per-tile schedule (4 barriers):
//   waitcnt vmcnt(16|8) ; barrier          <- tile t's DMA done, t+1 in flight
//   ds_read halo/main/Hsrc -> regs ; FMA   <- compute from buf[cur]
//   barrier ; ds_write outputs + H update
//   barrier ; ds_read streamout -> regs
//   barrier ; global_store 2KB-contig ; issue DMA t+2 -> buf[cur]

typedef float f32x4 __attribute__((ext_vector_type(4)));

#define T_LEN 4096
#define H_DIM 16
#define ROW_B 256                         // bytes per row (D=64 fp32)
#define HALO 16
#define MAIN 64                           // rows per tile
#define TILE_B (MAIN * ROW_B)             // 16384
#define HALO_B (HALO * ROW_B)             // 4096
#define THREADS 128                       // 8 chunks x 16 d4 = 2 waves
#define NWAVES 2
#define CHUNK 8                           // rows per thread
#define SPANS 8                           // spans per (b,h)
#define SPAN_ROWS (T_LEN / SPANS)         // 512
#define NT (SPAN_ROWS / MAIN)             // 8 tiles per block
#define DMA_PW (TILE_B / NWAVES / 1024)   // 8 DMA instrs per wave per tile

__device__ __forceinline__ f32x4 fma4(float a, f32x4 y, f32x4 kv) {
  f32x4 r;
  r.x = fmaf(a, y.x, kv.x);
  r.y = fmaf(a, y.y, kv.y);
  r.z = fmaf(a, y.z, kv.z);
  r.w = fmaf(a, y.w, kv.w);
  return r;
}

__global__ __launch_bounds__(THREADS, 2) void leaky_avg_kernel(
    const float* __restrict__ k,
    const float* __restrict__ beta,
    float* __restrict__ out) {
  // 2 tile buffers + halo slot = 36 KB -> 4 blocks/CU
  __shared__ __align__(16) unsigned char lds[2 * TILE_B + HALO_B];
  unsigned char* buf0 = lds;
  unsigned char* buf1 = lds + TILE_B;
  f32x4* Hq = (f32x4*)(lds + 2 * TILE_B);   // 16 rows x 16 quads

  const int tid  = threadIdx.x;
  const int bid  = blockIdx.x;
  const int bh   = bid >> 3;                // SPANS = 8
  const int bc   = bid & (SPANS - 1);
  const int h    = bh & (H_DIM - 1);
  const float a  = expf(-fabsf(beta[h]) * 10.0f);

  const size_t span_byte = ((size_t)bh * T_LEN + (size_t)bc * SPAN_ROWS) * ROW_B;
  const char*  kc  = (const char*)k + span_byte;
  char*        oc  = (char*)out + span_byte;
  const int wave = tid >> 6, lane = tid & 63;

  const int c   = tid >> 4;                 // chunk 0..7
  const int d4i = tid & 15;

#define DMA_TILE(t, dst)                                                        \
  {                                                                             \
    const char* _s = kc + (size_t)(t) * TILE_B;                                 \
    _Pragma("unroll")                                                           \
    for (int _i = 0; _i < DMA_PW; ++_i) {                                       \
      int _o = (_i * NWAVES + wave) * 1024 + lane * 16;                         \
      __builtin_amdgcn_global_load_lds(                                         \
          (const __attribute__((address_space(1))) void*)(_s + _o),             \
          (__attribute__((address_space(3))) void*)((dst) + _o), 16, 0, 0);     \
    }                                                                           \
  }

  // ---- prologue: DMA tile0, (halo if bc>0), tile1 ----
  DMA_TILE(0, buf0);
  if (bc > 0) {
    const char* hs = kc - HALO_B;
    #pragma unroll
    for (int i = 0; i < 2; ++i) {           // 4 KB over 2 waves
      int o = (i * NWAVES + wave) * 1024 + lane * 16;
      __builtin_amdgcn_global_load_lds(
          (const __attribute__((address_space(1))) void*)(hs + o),
          (__attribute__((address_space(3))) void*)(lds + 2 * TILE_B + o), 16, 0, 0);
    }
  }
  DMA_TILE(1, buf1);

  unsigned char* bufs[2] = { buf0, buf1 };
  int cur = 0;

  #pragma unroll 1
  for (int t = 0; t < NT; ++t) {
    // 1. counted wait: tile t's DMA (+span halo at t==0) retired;
    //    steady state leaves [stores_{t-1}(8), DMA_{t+1}(8)] outstanding.
    if (t == 0 || t == NT - 1) {
      asm volatile("s_waitcnt vmcnt(8)" ::: "memory");
    } else {
      asm volatile("s_waitcnt vmcnt(16)" ::: "memory");
    }
    __builtin_amdgcn_sched_barrier(0);
    __syncthreads();

    const f32x4* B = (const f32x4*)bufs[cur];
    const bool first = (bc == 0 && t == 0);   // span of t=0: scan starts at zero

    // ---- compute: halo warm-up then CHUNK main rows ----
    f32x4 y = {0.f, 0.f, 0.f, 0.f};
    if (c == 0) {
      if (!first) {
        #pragma unroll
        for (int s = 0; s < 16; ++s) y = fma4(a, y, Hq[s * 16 + d4i]);
      }
    } else if (c == 1) {
      if (!first) {                           // rows -8..-1 live in H[8..15]
        #pragma unroll
        for (int s = 8; s < 16; ++s) y = fma4(a, y, Hq[s * 16 + d4i]);
      }
      #pragma unroll
      for (int r = 0; r < 8; ++r) y = fma4(a, y, B[r * 16 + d4i]);
    } else {
      #pragma unroll
      for (int s = 0; s < 16; ++s) y = fma4(a, y, B[(c * 8 - 16 + s) * 16 + d4i]);
    }

    f32x4 yb[CHUNK];
    #pragma unroll
    for (int s = 0; s < CHUNK; ++s) {
      y = fma4(a, y, B[(c * 8 + s) * 16 + d4i]);
      yb[s] = y;
    }

    // H-update source: INPUT rows MAIN-16..MAIN-1, read before overwrite
    f32x4 hc[2];
    #pragma unroll
    for (int i = 0; i < 2; ++i) {
      int idx = i * THREADS + tid;            // 0..255 over 16 rows x 16 quads
      hc[i] = B[(MAIN - HALO + (idx >> 4)) * 16 + (idx & 15)];
    }
    __syncthreads();                          // all reads of buf[cur] + H done

    // ---- writes: outputs in place, H update ----
    f32x4* Bw = (f32x4*)bufs[cur];
    #pragma unroll
    for (int s = 0; s < CHUNK; ++s) Bw[(c * 8 + s) * 16 + d4i] = yb[s];
    #pragma unroll
    for (int i = 0; i < 2; ++i) Hq[i * THREADS + tid] = hc[i];
    __syncthreads();

    // ---- streamout: LDS -> regs (linear, conflict-free) ----
    f32x4 so[8];
    #pragma unroll
    for (int i = 0; i < 8; ++i) so[i] = ((const f32x4*)bufs[cur])[i * THREADS + tid];
    __syncthreads();                          // buf[cur] free for DMA t+2

    // ---- stores (2 KB contiguous slices) then next DMA: never drain vmcnt ----
    char* od = oc + (size_t)t * TILE_B;
    #pragma unroll
    for (int i = 0; i < 8; ++i)
      *(f32x4*)(od + (size_t)(i * THREADS + tid) * 16) = so[i];

    if (t + 2 < NT) DMA_TILE(t + 2, bufs[cur]);
    cur ^= 1;
  }
}

extern "C" void kernel_launch(void* const* d_in, const int* in_sizes, int n_in,
                              void* d_out, int out_size, void* d_ws, size_t ws_size,
                              hipStream_t stream) {
  const float* k    = (const float*)d_in[0];   // (8,16,4096,64) fp32
  const float* beta = (const float*)d_in[1];   // (1,16,1,1) fp32
  float*       out  = (float*)d_out;           // (8,16,4096,64) fp32

  // blocks = B*H * SPANS = 128 * 8 = 1024, 128 threads each (4 blocks/CU)
  leaky_avg_kernel<<<dim3(128 * SPANS), dim3(THREADS), 0, stream>>>(k, beta, out);
}